// Round 11
// baseline (181.064 us; speedup 1.0000x reference)
//
#include <hip/hip_runtime.h>

#define E 1024
#define SEQ 2048
#define BATCH 2
#define NH 16
#define DK 64
#define NKW (SEQ / 64)
#define LOG2E 1.44269504f

typedef short s16x8 __attribute__((ext_vector_type(8)));
typedef float f32x4 __attribute__((ext_vector_type(4)));

static __device__ __forceinline__ unsigned short f2bf(float f) {
    union { float f; unsigned int u; } c; c.f = f;
    unsigned int u = c.u;
    return (unsigned short)((u + 0x7FFFu + ((u >> 16) & 1u)) >> 16);
}

static __device__ __forceinline__ void gld_lds16(const unsigned short* g, unsigned short* l) {
    __builtin_amdgcn_global_load_lds((const __attribute__((address_space(1))) void*)g,
                                     (__attribute__((address_space(3))) void*)l, 16, 0, 0);
}

// ---------------- fused prep: wprep x4 | act2bf x3 | maskpack ---------------
__global__ __launch_bounds__(256) void prep(const float* __restrict__ w0, const float* __restrict__ w1,
                                            const float* __restrict__ w2, const float* __restrict__ w3,
                                            unsigned short* __restrict__ wt,
                                            const float* __restrict__ a0, const float* __restrict__ a1,
                                            const float* __restrict__ a2, unsigned short* __restrict__ abf,
                                            const int* __restrict__ mask,
                                            unsigned long long* __restrict__ mp) {
    const int bid = blockIdx.x;
    if (bid < 4096) {
        __shared__ float t[32][33];
        const int z = bid >> 10, rem = bid & 1023;
        const float* w = z == 0 ? w0 : z == 1 ? w1 : z == 2 ? w2 : w3;
        unsigned short* o = wt + (size_t)z * E * E;
        const int bx = (rem & 31) * 32, by = (rem >> 5) * 32;
        const int tx = threadIdx.x & 31, ty = threadIdx.x >> 5;
        for (int i = 0; i < 32; i += 8)
            t[ty + i][tx] = w[(size_t)(by + ty + i) * E + bx + tx];
        __syncthreads();
        for (int i = 0; i < 32; i += 8)
            o[(size_t)(bx + ty + i) * E + by + tx] = f2bf(t[tx][ty + i]);
    } else if (bid < 10240) {
        const int idx = bid - 4096;
        const int y = idx >> 11, x = idx & 2047;
        const float* s = y == 0 ? a0 : y == 1 ? a1 : a2;
        unsigned short* d = abf + (size_t)y * BATCH * SEQ * E;
        const size_t i = ((size_t)x * 256 + threadIdx.x) * 8;
        const float4 v0 = *(const float4*)&s[i];
        const float4 v1 = *(const float4*)&s[i + 4];
        s16x8 v;
        v[0] = (short)f2bf(v0.x); v[1] = (short)f2bf(v0.y); v[2] = (short)f2bf(v0.z); v[3] = (short)f2bf(v0.w);
        v[4] = (short)f2bf(v1.x); v[5] = (short)f2bf(v1.y); v[6] = (short)f2bf(v1.z); v[7] = (short)f2bf(v1.w);
        *(s16x8*)&d[i] = v;
    } else {
        const int bm = bid - 10240;
        const int w = threadIdx.x >> 6, l = threadIdx.x & 63;
        const size_t wbase = ((size_t)bm * 4 + w) * 16;
        for (int i = 0; i < 16; i++) {
            const size_t widx = wbase + i;  // = (b*SEQ + q)*NKW + t
            const int mv = mask[widx * 64 + l];
            const unsigned long long bits = __ballot(mv != 0);
            if (l == 0) mp[widx] = bits;
        }
    }
}

// ---------------- m97-style GEMM: C = (A @ Bt^T + bias) * scale -------------
// V_TRANS: for z==2 (V projection), write V^T [b*E+e][s] directly via an LDS
// transpose epilogue (replaces the separate vtrans kernel). Block-uniform
// control flow; plain barriers; no cross-iteration aliasing.
template <int OUT_F32, int N_BATCH, int V_TRANS>
__global__ __launch_bounds__(256) void gemm128(const unsigned short* __restrict__ A,
                                               const unsigned short* __restrict__ Bt,
                                               const float* __restrict__ b0,
                                               const float* __restrict__ b1,
                                               const float* __restrict__ b2,
                                               void* __restrict__ Cv,
                                               unsigned short* __restrict__ vtp,
                                               float scale0) {
    __shared__ __attribute__((aligned(16))) unsigned short As[128 * 32];
    __shared__ __attribute__((aligned(16))) unsigned short Bs[128 * 32];
    __shared__ __attribute__((aligned(16))) unsigned short Tt[64 * 128];
    const int z = N_BATCH > 1 ? blockIdx.z : 0;
    const float* bias = z == 0 ? b0 : z == 1 ? b1 : b2;
    const float scale = (N_BATCH > 1 && z > 0) ? 1.0f : scale0;
    A += (size_t)z * BATCH * SEQ * E;
    Bt += (size_t)z * E * E;

    const int tid = threadIdx.x;
    const int w = tid >> 6, l = tid & 63;
    const int lg = l >> 4, lr = l & 15;
    const int m0 = blockIdx.y * 128, n0 = blockIdx.x * 128;
    const int wr = (w >> 1) * 64, wc = (w & 1) * 64;

    const int srow = w * 16 + (l >> 2);
    const int scol = (l & 3) * 8;
    const unsigned short* gA = A + (size_t)(m0 + srow) * E + scol;
    const unsigned short* gB = Bt + (size_t)(n0 + srow) * E + scol;
    unsigned short* lA = As + w * 16 * 32;
    unsigned short* lB = Bs + w * 16 * 32;

    f32x4 acc[4][4] = {};

    for (int k0 = 0; k0 < E; k0 += 32) {
        __syncthreads();
        gld_lds16(gA + k0, lA);
        gld_lds16(gA + (size_t)64 * E + k0, lA + 64 * 32);
        gld_lds16(gB + k0, lB);
        gld_lds16(gB + (size_t)64 * E + k0, lB + 64 * 32);
        __syncthreads();
        s16x8 af[4], bf[4];
#pragma unroll
        for (int i = 0; i < 4; i++)
            af[i] = *(const s16x8*)&As[(wr + i * 16 + lr) * 32 + lg * 8];
#pragma unroll
        for (int j = 0; j < 4; j++)
            bf[j] = *(const s16x8*)&Bs[(wc + j * 16 + lr) * 32 + lg * 8];
        __builtin_amdgcn_s_setprio(1);
#pragma unroll
        for (int i = 0; i < 4; i++)
#pragma unroll
            for (int j = 0; j < 4; j++)
                acc[i][j] = __builtin_amdgcn_mfma_f32_16x16x32_bf16(af[i], bf[j], acc[i][j], 0, 0, 0);
        __builtin_amdgcn_s_setprio(0);
    }

    if (V_TRANS && z == 2) {
        // ---- transpose epilogue: C-tile -> LDS (swizzled) -> V^T stores ----
        const int bb = blockIdx.y >> 4;          // batch (16 m-tiles per batch)
        const int s0 = (blockIdx.y & 15) * 128;  // seq offset within batch
        for (int h = 0; h < 2; ++h) {
            __syncthreads();  // phase separation (also protects Tt reuse across h)
            if ((w & 1) == h) {
#pragma unroll
                for (int i = 0; i < 4; i++) {
#pragma unroll
                    for (int j = 0; j < 4; j++) {
                        const int nl = j * 16 + lr;            // 0..63 within half
                        const int m4 = (wr >> 2) + i * 4 + lg; // m/4 within tile
                        const float bv = bias[n0 + 64 * h + nl];
                        const unsigned long long e0 = f2bf(acc[i][j][0] + bv);
                        const unsigned long long e1 = f2bf(acc[i][j][1] + bv);
                        const unsigned long long e2 = f2bf(acc[i][j][2] + bv);
                        const unsigned long long e3 = f2bf(acc[i][j][3] + bv);
                        const unsigned long long pk = e0 | (e1 << 16) | (e2 << 32) | (e3 << 48);
                        const int off = nl * 256 + ((m4 * 8) ^ ((nl & 7) << 4));
                        *(unsigned long long*)((char*)Tt + off) = pk;
                    }
                }
            }
            __syncthreads();
#pragma unroll
            for (int p = 0; p < 4; p++) {
                const int nl = p * 16 + (tid >> 4);
                const int ub = (tid & 15) * 16;
                const int sw = (nl & 7) << 4;
                const unsigned long long lo = *(const unsigned long long*)((char*)Tt + nl * 256 + (ub ^ sw));
                const unsigned long long hi = *(const unsigned long long*)((char*)Tt + nl * 256 + ((ub + 8) ^ sw));
                ulonglong2 st; st.x = lo; st.y = hi;
                *(ulonglong2*)&vtp[((size_t)bb * E + n0 + 64 * h + nl) * SEQ + s0 + (tid & 15) * 8] = st;
            }
        }
        return;
    }

    unsigned short* Co = (unsigned short*)Cv + (size_t)z * BATCH * SEQ * E;
#pragma unroll
    for (int i = 0; i < 4; i++) {
#pragma unroll
        for (int j = 0; j < 4; j++) {
            const int n = n0 + wc + j * 16 + lr;
            const float bv = bias[n];
#pragma unroll
            for (int r = 0; r < 4; r++) {
                const int m = m0 + wr + i * 16 + lg * 4 + r;
                const float v = (acc[i][j][r] + bv) * scale;
                if (OUT_F32) ((float*)Cv)[(size_t)m * E + n] = v;
                else Co[(size_t)m * E + n] = f2bf(v);
            }
        }
    }
}

// ---------------- flash attention (R8-proven core, byte-exact revert) -------
// log2-domain online softmax, defer-max THR=8, row-sum via MFMA(P, ones).
// LDS 32 KB: K/V double-buffered [64][64] with swizzle ((row>>1)&7)<<4;
// P-relayout buffer ALIASED into Kl[1-buf] (dead half) — wave w's P region
// == exactly the rows wave w re-stages, so the overlap is wave-private.
// Mask u64 loads hoisted to loop TOP (latency hidden under QK^T MFMAs).
// FROZEN: R10 proved this design is schedule-sensitive (launch_bounds alone
// broke it) — do not perturb scheduling/sync here without a race-screen.
__global__ __launch_bounds__(256) void attn(const unsigned short* __restrict__ qb,
                                            const unsigned short* __restrict__ kb,
                                            const unsigned short* __restrict__ vbT,
                                            const unsigned long long* __restrict__ maskp,
                                            unsigned short* __restrict__ ctx) {
    __shared__ __attribute__((aligned(16))) unsigned short Kl[2][64 * 64];
    __shared__ __attribute__((aligned(16))) unsigned short Vl[2][64 * 64];

    const int tid = threadIdx.x;
    const int w = tid >> 6, l = tid & 63, lg = l >> 4, lr = l & 15;
    // XCD swizzle: each XCD gets 128 consecutive (b,h,qt) units = 4 whole heads
    const int u = (blockIdx.x & 7) * 128 + (blockIdx.x >> 3);
    const int qt = u & 31, h = (u >> 5) & 15, b = u >> 9;
    const int q0 = qt * 64 + w * 16;

    const unsigned short* qh = qb + (size_t)b * SEQ * E + h * DK;
    const unsigned short* kh = kb + (size_t)b * SEQ * E + h * DK;
    const unsigned short* vt = vbT + ((size_t)b * E + h * DK) * SEQ;
    const unsigned long long* mp = maskp + (size_t)b * SEQ * NKW;

    const s16x8 aq0 = *(const s16x8*)&qh[(size_t)(q0 + lr) * E + lg * 8];
    const s16x8 aq1 = *(const s16x8*)&qh[(size_t)(q0 + lr) * E + 32 + lg * 8];

    s16x8 bone;
#pragma unroll
    for (int i = 0; i < 8; i++) bone[i] = (short)0x3F80;  // bf16 1.0

    const int sr = tid >> 2, sc = (tid & 3) * 8;
    const unsigned short* gK = kh + (size_t)sr * E + sc;
    const unsigned short* gV = vt + (size_t)sr * SEQ + sc;
    const int ssw = ((sr >> 1) & 7) << 4;
    const int wsw0 = (sr * 128 + sc * 2) ^ ssw;
    const int wsw1 = (sr * 128 + sc * 2 + 64) ^ ssw;

    f32x4 o[4] = {};
    f32x4 osum = {};
    float mrun[4] = {-1e30f, -1e30f, -1e30f, -1e30f};

    s16x8 kr0, kr1, vr0, vr1;
    kr0 = *(const s16x8*)(gK);
    kr1 = *(const s16x8*)(gK + 32);
    vr0 = *(const s16x8*)(gV);
    vr1 = *(const s16x8*)(gV + 32);
    *(s16x8*)((char*)&Kl[0][0] + wsw0) = kr0;
    *(s16x8*)((char*)&Kl[0][0] + wsw1) = kr1;
    *(s16x8*)((char*)&Vl[0][0] + wsw0) = vr0;
    *(s16x8*)((char*)&Vl[0][0] + wsw1) = vr1;
    __syncthreads();

    for (int t = 0; t < NKW; ++t) {
        const int buf = t & 1;

        // ---- mask words for THIS tile, issued early (hidden under QK^T) ----
        unsigned long long mwv[4];
#pragma unroll
        for (int r = 0; r < 4; r++)
            mwv[r] = mp[(size_t)(q0 + lg * 4 + r) * NKW + t];

        // ---- K/V prefetch for t+1 ----
        if (t + 1 < NKW) {
            const size_t kof = (size_t)(t + 1) * 64;
            kr0 = *(const s16x8*)(gK + kof * E);
            kr1 = *(const s16x8*)(gK + kof * E + 32);
            vr0 = *(const s16x8*)(gV + kof);
            vr1 = *(const s16x8*)(gV + kof + 32);
        }

        // ---- QK^T (log2-domain scores; col lr of mfma kt = K row 2lr+..) ----
        f32x4 s[4] = {};
        const char* kbse = (const char*)&Kl[buf][0];
        __builtin_amdgcn_s_setprio(1);
#pragma unroll
        for (int kt = 0; kt < 4; kt++) {
            const int row = 2 * lr + (kt & 1) + 32 * (kt >> 1);
            const int sw = (lr & 7) << 4;  // == ((row>>1)&7)<<4
            const s16x8 b0 = *(const s16x8*)(kbse + row * 128 + ((lg << 4) ^ sw));
            const s16x8 b1 = *(const s16x8*)(kbse + row * 128 + ((64 + (lg << 4)) ^ sw));
            s[kt] = __builtin_amdgcn_mfma_f32_16x16x32_bf16(aq0, b0, s[kt], 0, 0, 0);
            s[kt] = __builtin_amdgcn_mfma_f32_16x16x32_bf16(aq1, b1, s[kt], 0, 0, 0);
        }
        __builtin_amdgcn_s_setprio(0);

        // ---- masked softmax: defer-max (THR=8 in log2 domain) ----
        // lane's scores: s[0]=k(2lr), s[1]=k(2lr+1), s[2]=k(2lr+32), s[3]=k(2lr+33)
        float v[4][4], pmax[4];
#pragma unroll
        for (int r = 0; r < 4; r++) {
            const unsigned long long mw = mwv[r];
            const unsigned int mlo = (unsigned int)mw, mhi = (unsigned int)(mw >> 32);
            v[r][0] = ((mlo >> (2 * lr)) & 1) ? s[0][r] : 1.442695e-8f;
            v[r][1] = ((mlo >> (2 * lr + 1)) & 1) ? s[1][r] : 1.442695e-8f;
            v[r][2] = ((mhi >> (2 * lr)) & 1) ? s[2][r] : 1.442695e-8f;
            v[r][3] = ((mhi >> (2 * lr + 1)) & 1) ? s[3][r] : 1.442695e-8f;
            pmax[r] = fmaxf(fmaxf(v[r][0], v[r][1]), fmaxf(v[r][2], v[r][3]));
        }
        const float dmax = fmaxf(fmaxf(pmax[0] - mrun[0], pmax[1] - mrun[1]),
                                 fmaxf(pmax[2] - mrun[2], pmax[3] - mrun[3]));
        if (!__all(dmax <= 8.0f)) {
#pragma unroll
            for (int r = 0; r < 4; r++) {
                float mx = pmax[r];
                mx = fmaxf(mx, __shfl_xor(mx, 1));
                mx = fmaxf(mx, __shfl_xor(mx, 2));
                mx = fmaxf(mx, __shfl_xor(mx, 4));
                mx = fmaxf(mx, __shfl_xor(mx, 8));
                const float mn = fmaxf(mrun[r], mx);
                const float alpha = __builtin_amdgcn_exp2f(mrun[r] - mn);
                mrun[r] = mn;
                osum[r] *= alpha;
#pragma unroll
                for (int dt = 0; dt < 4; dt++) o[dt][r] *= alpha;
            }
        }

        // ---- P = exp2(v - m) -> cvt_pk -> b32 writes into Kl[1-buf] (P region) ----
        char* plw = (char*)&Kl[buf ^ 1][0] + w * 2048;
#pragma unroll
        for (int r = 0; r < 4; r++) {
            const int q = lg * 4 + r;
            const float p0 = __builtin_amdgcn_exp2f(v[r][0] - mrun[r]);
            const float p1 = __builtin_amdgcn_exp2f(v[r][1] - mrun[r]);
            const float p2 = __builtin_amdgcn_exp2f(v[r][2] - mrun[r]);
            const float p3 = __builtin_amdgcn_exp2f(v[r][3] - mrun[r]);
            unsigned int pk01, pk23;
            asm("v_cvt_pk_bf16_f32 %0, %1, %2" : "=v"(pk01) : "v"(p0), "v"(p1));
            asm("v_cvt_pk_bf16_f32 %0, %1, %2" : "=v"(pk23) : "v"(p2), "v"(p3));
            const int psw = (q & 7) << 4;
            *(unsigned int*)(plw + q * 128 + ((lr * 4) ^ psw)) = pk01;       // k=2lr,2lr+1
            *(unsigned int*)(plw + q * 128 + ((64 + lr * 4) ^ psw)) = pk23;  // k=2lr+32,+33
        }
        const int swp = (lr & 7) << 4;
        const s16x8 ap0 = *(const s16x8*)(plw + lr * 128 + ((lg << 4) ^ swp));
        const s16x8 ap1 = *(const s16x8*)(plw + lr * 128 + ((64 + (lg << 4)) ^ swp));

        // ---- PV + row-sum via MFMA ----
        const char* vbse = (const char*)&Vl[buf][0];
        __builtin_amdgcn_s_setprio(1);
        osum = __builtin_amdgcn_mfma_f32_16x16x32_bf16(ap0, bone, osum, 0, 0, 0);
        osum = __builtin_amdgcn_mfma_f32_16x16x32_bf16(ap1, bone, osum, 0, 0, 0);
#pragma unroll
        for (int dt = 0; dt < 4; dt++) {
            const int row = dt * 16 + lr;
            const int sw = ((row >> 1) & 7) << 4;
            const s16x8 bv0 = *(const s16x8*)(vbse + row * 128 + ((lg << 4) ^ sw));
            const s16x8 bv1 = *(const s16x8*)(vbse + row * 128 + ((64 + (lg << 4)) ^ sw));
            o[dt] = __builtin_amdgcn_mfma_f32_16x16x32_bf16(ap0, bv0, o[dt], 0, 0, 0);
            o[dt] = __builtin_amdgcn_mfma_f32_16x16x32_bf16(ap1, bv1, o[dt], 0, 0, 0);
        }
        __builtin_amdgcn_s_setprio(0);

        // ---- stage next tile (wave w overwrites exactly its own P region) ----
        if (t + 1 < NKW) {
            const int nb = buf ^ 1;
            *(s16x8*)((char*)&Kl[nb][0] + wsw0) = kr0;
            *(s16x8*)((char*)&Kl[nb][0] + wsw1) = kr1;
            *(s16x8*)((char*)&Vl[nb][0] + wsw0) = vr0;
            *(s16x8*)((char*)&Vl[nb][0] + wsw1) = vr1;
        }
        __syncthreads();
    }

#pragma unroll
    for (int dt = 0; dt < 4; dt++) {
#pragma unroll
        for (int r = 0; r < 4; r++) {
            const int q = q0 + lg * 4 + r;
            const float val = o[dt][r] / osum[r];
            ctx[(size_t)(b * SEQ + q) * E + h * DK + dt * 16 + lr] = f2bf(val);
        }
    }
}

extern "C" void kernel_launch(void* const* d_in, const int* in_sizes, int n_in,
                              void* d_out, int out_size, void* d_ws, size_t ws_size,
                              hipStream_t stream) {
    const float* query = (const float*)d_in[0];
    const float* key   = (const float*)d_in[1];
    const float* value = (const float*)d_in[2];
    const int*   mask  = (const int*)d_in[3];
    const float* wq = (const float*)d_in[4];
    const float* bq = (const float*)d_in[5];
    const float* wk = (const float*)d_in[6];
    const float* bk = (const float*)d_in[7];
    const float* wv = (const float*)d_in[8];
    const float* bv = (const float*)d_in[9];
    const float* wo = (const float*)d_in[10];
    const float* bo = (const float*)d_in[11];

    unsigned short* wt   = (unsigned short*)d_ws;            // 4 x E x E (q,k,v,o)
    unsigned short* wt_o = wt + (size_t)3 * E * E;
    unsigned short* qbf  = wt + (size_t)4 * E * E;           // 3 x B*S*E contiguous
    unsigned short* qb   = qbf + (size_t)3 * BATCH * SEQ * E;  // q,k projected (+v slot unused)
    unsigned short* kb   = qb + (size_t)BATCH * SEQ * E;
    unsigned short* vb   = kb + (size_t)BATCH * SEQ * E;     // unused (V^T written directly)
    unsigned short* vbT  = vb + (size_t)BATCH * SEQ * E;
    unsigned short* ctx  = vbT + (size_t)BATCH * SEQ * E;
    unsigned long long* maskp = (unsigned long long*)(ctx + (size_t)BATCH * SEQ * E);

    prep<<<dim3(12288), 256, 0, stream>>>(wq, wk, wv, wo, wt, query, key, value, qbf, mask, maskp);

    // QKV projections batched; Q pre-scaled by 0.125*log2(e); V written transposed
    gemm128<0, 3, 1><<<dim3(E / 128, (BATCH * SEQ) / 128, 3), 256, 0, stream>>>(
        qbf, wt, bq, bk, bv, qb, vbT, 0.125f * LOG2E);

    attn<<<dim3(SEQ / 64 * NH * BATCH), 256, 0, stream>>>(qb, kb, vbT, maskp, ctx);

    gemm128<1, 1, 0><<<dim3(E / 128, (BATCH * SEQ) / 128), 256, 0, stream>>>(
        ctx, wt_o, bo, bo, bo, (float*)d_out, (unsigned short*)nullptr, 1.0f);
}

// Round 12
// 180.615 us; speedup vs baseline: 1.0025x; 1.0025x over previous
//
#include <hip/hip_runtime.h>

#define E 1024
#define SEQ 2048
#define BATCH 2
#define NH 16
#define DK 64
#define NKW (SEQ / 64)
#define LOG2E 1.44269504f

typedef short s16x8 __attribute__((ext_vector_type(8)));
typedef float f32x4 __attribute__((ext_vector_type(4)));

static __device__ __forceinline__ unsigned short f2bf(float f) {
    union { float f; unsigned int u; } c; c.f = f;
    unsigned int u = c.u;
    return (unsigned short)((u + 0x7FFFu + ((u >> 16) & 1u)) >> 16);
}

static __device__ __forceinline__ void gld_lds16(const unsigned short* g, unsigned short* l) {
    __builtin_amdgcn_global_load_lds((const __attribute__((address_space(1))) void*)g,
                                     (__attribute__((address_space(3))) void*)l, 16, 0, 0);
}

// ---------------- fused prep: wprep x4 | act2bf x3 | maskpack ---------------
__global__ __launch_bounds__(256) void prep(const float* __restrict__ w0, const float* __restrict__ w1,
                                            const float* __restrict__ w2, const float* __restrict__ w3,
                                            unsigned short* __restrict__ wt,
                                            const float* __restrict__ a0, const float* __restrict__ a1,
                                            const float* __restrict__ a2, unsigned short* __restrict__ abf,
                                            const int* __restrict__ mask,
                                            unsigned long long* __restrict__ mp) {
    const int bid = blockIdx.x;
    if (bid < 4096) {
        __shared__ float t[32][33];
        const int z = bid >> 10, rem = bid & 1023;
        const float* w = z == 0 ? w0 : z == 1 ? w1 : z == 2 ? w2 : w3;
        unsigned short* o = wt + (size_t)z * E * E;
        const int bx = (rem & 31) * 32, by = (rem >> 5) * 32;
        const int tx = threadIdx.x & 31, ty = threadIdx.x >> 5;
        for (int i = 0; i < 32; i += 8)
            t[ty + i][tx] = w[(size_t)(by + ty + i) * E + bx + tx];
        __syncthreads();
        for (int i = 0; i < 32; i += 8)
            o[(size_t)(bx + ty + i) * E + by + tx] = f2bf(t[tx][ty + i]);
    } else if (bid < 10240) {
        const int idx = bid - 4096;
        const int y = idx >> 11, x = idx & 2047;
        const float* s = y == 0 ? a0 : y == 1 ? a1 : a2;
        unsigned short* d = abf + (size_t)y * BATCH * SEQ * E;
        const size_t i = ((size_t)x * 256 + threadIdx.x) * 8;
        const float4 v0 = *(const float4*)&s[i];
        const float4 v1 = *(const float4*)&s[i + 4];
        s16x8 v;
        v[0] = (short)f2bf(v0.x); v[1] = (short)f2bf(v0.y); v[2] = (short)f2bf(v0.z); v[3] = (short)f2bf(v0.w);
        v[4] = (short)f2bf(v1.x); v[5] = (short)f2bf(v1.y); v[6] = (short)f2bf(v1.z); v[7] = (short)f2bf(v1.w);
        *(s16x8*)&d[i] = v;
    } else {
        const int bm = bid - 10240;
        const int w = threadIdx.x >> 6, l = threadIdx.x & 63;
        const size_t wbase = ((size_t)bm * 4 + w) * 16;
        for (int i = 0; i < 16; i++) {
            const size_t widx = wbase + i;  // = (b*SEQ + q)*NKW + t
            const int mv = mask[widx * 64 + l];
            const unsigned long long bits = __ballot(mv != 0);
            if (l == 0) mp[widx] = bits;
        }
    }
}

// ---------------- m97-style GEMM: C = (A @ Bt^T + bias) * scale -------------
// V_TRANS: for z==2 (V projection), write V^T [b*E+e][s] directly via an LDS
// transpose epilogue. Tt ALIASES As/Bs (dead after the K-loop; the epilogue's
// leading barrier separates last As/Bs reads from first Tt writes) -> LDS
// stays 16 KB for every instantiation (R11 regression: separate 16KB Tt
// raised LDS to 48KB and halved QKV-gemm occupancy).
template <int OUT_F32, int N_BATCH, int V_TRANS>
__global__ __launch_bounds__(256) void gemm128(const unsigned short* __restrict__ A,
                                               const unsigned short* __restrict__ Bt,
                                               const float* __restrict__ b0,
                                               const float* __restrict__ b1,
                                               const float* __restrict__ b2,
                                               void* __restrict__ Cv,
                                               unsigned short* __restrict__ vtp,
                                               float scale0) {
    __shared__ __attribute__((aligned(16))) unsigned short SMEM[128 * 32 * 2];
    unsigned short* As = SMEM;             // 128x32
    unsigned short* Bs = SMEM + 128 * 32;  // 128x32
    const int z = N_BATCH > 1 ? blockIdx.z : 0;
    const float* bias = z == 0 ? b0 : z == 1 ? b1 : b2;
    const float scale = (N_BATCH > 1 && z > 0) ? 1.0f : scale0;
    A += (size_t)z * BATCH * SEQ * E;
    Bt += (size_t)z * E * E;

    const int tid = threadIdx.x;
    const int w = tid >> 6, l = tid & 63;
    const int lg = l >> 4, lr = l & 15;
    const int m0 = blockIdx.y * 128, n0 = blockIdx.x * 128;
    const int wr = (w >> 1) * 64, wc = (w & 1) * 64;

    const int srow = w * 16 + (l >> 2);
    const int scol = (l & 3) * 8;
    const unsigned short* gA = A + (size_t)(m0 + srow) * E + scol;
    const unsigned short* gB = Bt + (size_t)(n0 + srow) * E + scol;
    unsigned short* lA = As + w * 16 * 32;
    unsigned short* lB = Bs + w * 16 * 32;

    f32x4 acc[4][4] = {};

    for (int k0 = 0; k0 < E; k0 += 32) {
        __syncthreads();
        gld_lds16(gA + k0, lA);
        gld_lds16(gA + (size_t)64 * E + k0, lA + 64 * 32);
        gld_lds16(gB + k0, lB);
        gld_lds16(gB + (size_t)64 * E + k0, lB + 64 * 32);
        __syncthreads();
        s16x8 af[4], bf[4];
#pragma unroll
        for (int i = 0; i < 4; i++)
            af[i] = *(const s16x8*)&As[(wr + i * 16 + lr) * 32 + lg * 8];
#pragma unroll
        for (int j = 0; j < 4; j++)
            bf[j] = *(const s16x8*)&Bs[(wc + j * 16 + lr) * 32 + lg * 8];
        __builtin_amdgcn_s_setprio(1);
#pragma unroll
        for (int i = 0; i < 4; i++)
#pragma unroll
            for (int j = 0; j < 4; j++)
                acc[i][j] = __builtin_amdgcn_mfma_f32_16x16x32_bf16(af[i], bf[j], acc[i][j], 0, 0, 0);
        __builtin_amdgcn_s_setprio(0);
    }

    if (V_TRANS && z == 2) {
        // ---- transpose epilogue: C-tile -> LDS (swizzled, aliases As/Bs) ----
        char* Tt = (char*)SMEM;                  // 64 rows x 256 bytes
        const int bb = blockIdx.y >> 4;          // batch (16 m-tiles per batch)
        const int s0 = (blockIdx.y & 15) * 128;  // seq offset within batch
        for (int h = 0; h < 2; ++h) {
            __syncthreads();  // separates prior LDS reads from Tt writes
            if ((w & 1) == h) {
#pragma unroll
                for (int i = 0; i < 4; i++) {
#pragma unroll
                    for (int j = 0; j < 4; j++) {
                        const int nl = j * 16 + lr;            // 0..63 within half
                        const int m4 = (wr >> 2) + i * 4 + lg; // m/4 within tile
                        const float bv = bias[n0 + 64 * h + nl];
                        const unsigned long long e0 = f2bf(acc[i][j][0] + bv);
                        const unsigned long long e1 = f2bf(acc[i][j][1] + bv);
                        const unsigned long long e2 = f2bf(acc[i][j][2] + bv);
                        const unsigned long long e3 = f2bf(acc[i][j][3] + bv);
                        const unsigned long long pk = e0 | (e1 << 16) | (e2 << 32) | (e3 << 48);
                        const int off = nl * 256 + ((m4 * 8) ^ ((nl & 7) << 4));
                        *(unsigned long long*)(Tt + off) = pk;
                    }
                }
            }
            __syncthreads();
#pragma unroll
            for (int p = 0; p < 4; p++) {
                const int nl = p * 16 + (tid >> 4);
                const int ub = (tid & 15) * 16;
                const int sw = (nl & 7) << 4;
                const unsigned long long lo = *(const unsigned long long*)(Tt + nl * 256 + (ub ^ sw));
                const unsigned long long hi = *(const unsigned long long*)(Tt + nl * 256 + ((ub + 8) ^ sw));
                ulonglong2 st; st.x = lo; st.y = hi;
                *(ulonglong2*)&vtp[((size_t)bb * E + n0 + 64 * h + nl) * SEQ + s0 + (tid & 15) * 8] = st;
            }
        }
        return;
    }

    unsigned short* Co = (unsigned short*)Cv + (size_t)z * BATCH * SEQ * E;
#pragma unroll
    for (int i = 0; i < 4; i++) {
#pragma unroll
        for (int j = 0; j < 4; j++) {
            const int n = n0 + wc + j * 16 + lr;
            const float bv = bias[n];
#pragma unroll
            for (int r = 0; r < 4; r++) {
                const int m = m0 + wr + i * 16 + lg * 4 + r;
                const float v = (acc[i][j][r] + bv) * scale;
                if (OUT_F32) ((float*)Cv)[(size_t)m * E + n] = v;
                else Co[(size_t)m * E + n] = f2bf(v);
            }
        }
    }
}

// ---------------- flash attention (R8-proven core, byte-exact) --------------
// log2-domain online softmax, defer-max THR=8, row-sum via MFMA(P, ones).
// LDS 32 KB: K/V double-buffered [64][64] with swizzle ((row>>1)&7)<<4;
// P-relayout buffer ALIASED into Kl[1-buf] (dead half) — wave w's P region
// == exactly the rows wave w re-stages, so the overlap is wave-private.
// Mask u64 loads hoisted to loop TOP (latency hidden under QK^T MFMAs).
// FROZEN: R10 proved this design is schedule-sensitive (launch_bounds alone
// broke it) — do not perturb scheduling/sync here without a race-screen.
__global__ __launch_bounds__(256) void attn(const unsigned short* __restrict__ qb,
                                            const unsigned short* __restrict__ kb,
                                            const unsigned short* __restrict__ vbT,
                                            const unsigned long long* __restrict__ maskp,
                                            unsigned short* __restrict__ ctx) {
    __shared__ __attribute__((aligned(16))) unsigned short Kl[2][64 * 64];
    __shared__ __attribute__((aligned(16))) unsigned short Vl[2][64 * 64];

    const int tid = threadIdx.x;
    const int w = tid >> 6, l = tid & 63, lg = l >> 4, lr = l & 15;
    // XCD swizzle: each XCD gets 128 consecutive (b,h,qt) units = 4 whole heads
    const int u = (blockIdx.x & 7) * 128 + (blockIdx.x >> 3);
    const int qt = u & 31, h = (u >> 5) & 15, b = u >> 9;
    const int q0 = qt * 64 + w * 16;

    const unsigned short* qh = qb + (size_t)b * SEQ * E + h * DK;
    const unsigned short* kh = kb + (size_t)b * SEQ * E + h * DK;
    const unsigned short* vt = vbT + ((size_t)b * E + h * DK) * SEQ;
    const unsigned long long* mp = maskp + (size_t)b * SEQ * NKW;

    const s16x8 aq0 = *(const s16x8*)&qh[(size_t)(q0 + lr) * E + lg * 8];
    const s16x8 aq1 = *(const s16x8*)&qh[(size_t)(q0 + lr) * E + 32 + lg * 8];

    s16x8 bone;
#pragma unroll
    for (int i = 0; i < 8; i++) bone[i] = (short)0x3F80;  // bf16 1.0

    const int sr = tid >> 2, sc = (tid & 3) * 8;
    const unsigned short* gK = kh + (size_t)sr * E + sc;
    const unsigned short* gV = vt + (size_t)sr * SEQ + sc;
    const int ssw = ((sr >> 1) & 7) << 4;
    const int wsw0 = (sr * 128 + sc * 2) ^ ssw;
    const int wsw1 = (sr * 128 + sc * 2 + 64) ^ ssw;

    f32x4 o[4] = {};
    f32x4 osum = {};
    float mrun[4] = {-1e30f, -1e30f, -1e30f, -1e30f};

    s16x8 kr0, kr1, vr0, vr1;
    kr0 = *(const s16x8*)(gK);
    kr1 = *(const s16x8*)(gK + 32);
    vr0 = *(const s16x8*)(gV);
    vr1 = *(const s16x8*)(gV + 32);
    *(s16x8*)((char*)&Kl[0][0] + wsw0) = kr0;
    *(s16x8*)((char*)&Kl[0][0] + wsw1) = kr1;
    *(s16x8*)((char*)&Vl[0][0] + wsw0) = vr0;
    *(s16x8*)((char*)&Vl[0][0] + wsw1) = vr1;
    __syncthreads();

    for (int t = 0; t < NKW; ++t) {
        const int buf = t & 1;

        // ---- mask words for THIS tile, issued early (hidden under QK^T) ----
        unsigned long long mwv[4];
#pragma unroll
        for (int r = 0; r < 4; r++)
            mwv[r] = mp[(size_t)(q0 + lg * 4 + r) * NKW + t];

        // ---- K/V prefetch for t+1 ----
        if (t + 1 < NKW) {
            const size_t kof = (size_t)(t + 1) * 64;
            kr0 = *(const s16x8*)(gK + kof * E);
            kr1 = *(const s16x8*)(gK + kof * E + 32);
            vr0 = *(const s16x8*)(gV + kof);
            vr1 = *(const s16x8*)(gV + kof + 32);
        }

        // ---- QK^T (log2-domain scores; col lr of mfma kt = K row 2lr+..) ----
        f32x4 s[4] = {};
        const char* kbse = (const char*)&Kl[buf][0];
        __builtin_amdgcn_s_setprio(1);
#pragma unroll
        for (int kt = 0; kt < 4; kt++) {
            const int row = 2 * lr + (kt & 1) + 32 * (kt >> 1);
            const int sw = (lr & 7) << 4;  // == ((row>>1)&7)<<4
            const s16x8 b0 = *(const s16x8*)(kbse + row * 128 + ((lg << 4) ^ sw));
            const s16x8 b1 = *(const s16x8*)(kbse + row * 128 + ((64 + (lg << 4)) ^ sw));
            s[kt] = __builtin_amdgcn_mfma_f32_16x16x32_bf16(aq0, b0, s[kt], 0, 0, 0);
            s[kt] = __builtin_amdgcn_mfma_f32_16x16x32_bf16(aq1, b1, s[kt], 0, 0, 0);
        }
        __builtin_amdgcn_s_setprio(0);

        // ---- masked softmax: defer-max (THR=8 in log2 domain) ----
        // lane's scores: s[0]=k(2lr), s[1]=k(2lr+1), s[2]=k(2lr+32), s[3]=k(2lr+33)
        float v[4][4], pmax[4];
#pragma unroll
        for (int r = 0; r < 4; r++) {
            const unsigned long long mw = mwv[r];
            const unsigned int mlo = (unsigned int)mw, mhi = (unsigned int)(mw >> 32);
            v[r][0] = ((mlo >> (2 * lr)) & 1) ? s[0][r] : 1.442695e-8f;
            v[r][1] = ((mlo >> (2 * lr + 1)) & 1) ? s[1][r] : 1.442695e-8f;
            v[r][2] = ((mhi >> (2 * lr)) & 1) ? s[2][r] : 1.442695e-8f;
            v[r][3] = ((mhi >> (2 * lr + 1)) & 1) ? s[3][r] : 1.442695e-8f;
            pmax[r] = fmaxf(fmaxf(v[r][0], v[r][1]), fmaxf(v[r][2], v[r][3]));
        }
        const float dmax = fmaxf(fmaxf(pmax[0] - mrun[0], pmax[1] - mrun[1]),
                                 fmaxf(pmax[2] - mrun[2], pmax[3] - mrun[3]));
        if (!__all(dmax <= 8.0f)) {
#pragma unroll
            for (int r = 0; r < 4; r++) {
                float mx = pmax[r];
                mx = fmaxf(mx, __shfl_xor(mx, 1));
                mx = fmaxf(mx, __shfl_xor(mx, 2));
                mx = fmaxf(mx, __shfl_xor(mx, 4));
                mx = fmaxf(mx, __shfl_xor(mx, 8));
                const float mn = fmaxf(mrun[r], mx);
                const float alpha = __builtin_amdgcn_exp2f(mrun[r] - mn);
                mrun[r] = mn;
                osum[r] *= alpha;
#pragma unroll
                for (int dt = 0; dt < 4; dt++) o[dt][r] *= alpha;
            }
        }

        // ---- P = exp2(v - m) -> cvt_pk -> b32 writes into Kl[1-buf] (P region) ----
        char* plw = (char*)&Kl[buf ^ 1][0] + w * 2048;
#pragma unroll
        for (int r = 0; r < 4; r++) {
            const int q = lg * 4 + r;
            const float p0 = __builtin_amdgcn_exp2f(v[r][0] - mrun[r]);
            const float p1 = __builtin_amdgcn_exp2f(v[r][1] - mrun[r]);
            const float p2 = __builtin_amdgcn_exp2f(v[r][2] - mrun[r]);
            const float p3 = __builtin_amdgcn_exp2f(v[r][3] - mrun[r]);
            unsigned int pk01, pk23;
            asm("v_cvt_pk_bf16_f32 %0, %1, %2" : "=v"(pk01) : "v"(p0), "v"(p1));
            asm("v_cvt_pk_bf16_f32 %0, %1, %2" : "=v"(pk23) : "v"(p2), "v"(p3));
            const int psw = (q & 7) << 4;
            *(unsigned int*)(plw + q * 128 + ((lr * 4) ^ psw)) = pk01;       // k=2lr,2lr+1
            *(unsigned int*)(plw + q * 128 + ((64 + lr * 4) ^ psw)) = pk23;  // k=2lr+32,+33
        }
        const int swp = (lr & 7) << 4;
        const s16x8 ap0 = *(const s16x8*)(plw + lr * 128 + ((lg << 4) ^ swp));
        const s16x8 ap1 = *(const s16x8*)(plw + lr * 128 + ((64 + (lg << 4)) ^ swp));

        // ---- PV + row-sum via MFMA ----
        const char* vbse = (const char*)&Vl[buf][0];
        __builtin_amdgcn_s_setprio(1);
        osum = __builtin_amdgcn_mfma_f32_16x16x32_bf16(ap0, bone, osum, 0, 0, 0);
        osum = __builtin_amdgcn_mfma_f32_16x16x32_bf16(ap1, bone, osum, 0, 0, 0);
#pragma unroll
        for (int dt = 0; dt < 4; dt++) {
            const int row = dt * 16 + lr;
            const int sw = ((row >> 1) & 7) << 4;
            const s16x8 bv0 = *(const s16x8*)(vbse + row * 128 + ((lg << 4) ^ sw));
            const s16x8 bv1 = *(const s16x8*)(vbse + row * 128 + ((64 + (lg << 4)) ^ sw));
            o[dt] = __builtin_amdgcn_mfma_f32_16x16x32_bf16(ap0, bv0, o[dt], 0, 0, 0);
            o[dt] = __builtin_amdgcn_mfma_f32_16x16x32_bf16(ap1, bv1, o[dt], 0, 0, 0);
        }
        __builtin_amdgcn_s_setprio(0);

        // ---- stage next tile (wave w overwrites exactly its own P region) ----
        if (t + 1 < NKW) {
            const int nb = buf ^ 1;
            *(s16x8*)((char*)&Kl[nb][0] + wsw0) = kr0;
            *(s16x8*)((char*)&Kl[nb][0] + wsw1) = kr1;
            *(s16x8*)((char*)&Vl[nb][0] + wsw0) = vr0;
            *(s16x8*)((char*)&Vl[nb][0] + wsw1) = vr1;
        }
        __syncthreads();
    }

#pragma unroll
    for (int dt = 0; dt < 4; dt++) {
#pragma unroll
        for (int r = 0; r < 4; r++) {
            const int q = q0 + lg * 4 + r;
            const float val = o[dt][r] / osum[r];
            ctx[(size_t)(b * SEQ + q) * E + h * DK + dt * 16 + lr] = f2bf(val);
        }
    }
}

extern "C" void kernel_launch(void* const* d_in, const int* in_sizes, int n_in,
                              void* d_out, int out_size, void* d_ws, size_t ws_size,
                              hipStream_t stream) {
    const float* query = (const float*)d_in[0];
    const float* key   = (const float*)d_in[1];
    const float* value = (const float*)d_in[2];
    const int*   mask  = (const int*)d_in[3];
    const float* wq = (const float*)d_in[4];
    const float* bq = (const float*)d_in[5];
    const float* wk = (const float*)d_in[6];
    const float* bk = (const float*)d_in[7];
    const float* wv = (const float*)d_in[8];
    const float* bv = (const float*)d_in[9];
    const float* wo = (const float*)d_in[10];
    const float* bo = (const float*)d_in[11];

    unsigned short* wt   = (unsigned short*)d_ws;            // 4 x E x E (q,k,v,o)
    unsigned short* wt_o = wt + (size_t)3 * E * E;
    unsigned short* qbf  = wt + (size_t)4 * E * E;           // 3 x B*S*E contiguous
    unsigned short* qb   = qbf + (size_t)3 * BATCH * SEQ * E;  // q,k projected (+v slot unused)
    unsigned short* kb   = qb + (size_t)BATCH * SEQ * E;
    unsigned short* vb   = kb + (size_t)BATCH * SEQ * E;     // unused (V^T written directly)
    unsigned short* vbT  = vb + (size_t)BATCH * SEQ * E;
    unsigned short* ctx  = vbT + (size_t)BATCH * SEQ * E;
    unsigned long long* maskp = (unsigned long long*)(ctx + (size_t)BATCH * SEQ * E);

    prep<<<dim3(12288), 256, 0, stream>>>(wq, wk, wv, wo, wt, query, key, value, qbf, mask, maskp);

    // QKV projections batched; Q pre-scaled by 0.125*log2(e); V written transposed
    gemm128<0, 3, 1><<<dim3(E / 128, (BATCH * SEQ) / 128, 3), 256, 0, stream>>>(
        qbf, wt, bq, bk, bv, qb, vbT, 0.125f * LOG2E);

    attn<<<dim3(SEQ / 64 * NH * BATCH), 256, 0, stream>>>(qb, kb, vbT, maskp, ctx);

    gemm128<1, 1, 0><<<dim3(E / 128, (BATCH * SEQ) / 128), 256, 0, stream>>>(
        ctx, wt_o, bo, bo, bo, (float*)d_out, (unsigned short*)nullptr, 1.0f);
}

// Round 14
// 171.044 us; speedup vs baseline: 1.0586x; 1.0560x over previous
//
#include <hip/hip_runtime.h>

#define E 1024
#define SEQ 2048
#define BATCH 2
#define NH 16
#define DK 64
#define NKW (SEQ / 64)
#define LOG2E 1.44269504f

typedef short s16x8 __attribute__((ext_vector_type(8)));
typedef float f32x4 __attribute__((ext_vector_type(4)));

static __device__ __forceinline__ unsigned short f2bf(float f) {
    union { float f; unsigned int u; } c; c.f = f;
    unsigned int u = c.u;
    return (unsigned short)((u + 0x7FFFu + ((u >> 16) & 1u)) >> 16);
}

static __device__ __forceinline__ void gld_lds16(const unsigned short* g, unsigned short* l) {
    __builtin_amdgcn_global_load_lds((const __attribute__((address_space(1))) void*)g,
                                     (__attribute__((address_space(3))) void*)l, 16, 0, 0);
}

// ---------------- fused prep: wprep x4 | act2bf x3 | maskpack ---------------
__global__ __launch_bounds__(256) void prep(const float* __restrict__ w0, const float* __restrict__ w1,
                                            const float* __restrict__ w2, const float* __restrict__ w3,
                                            unsigned short* __restrict__ wt,
                                            const float* __restrict__ a0, const float* __restrict__ a1,
                                            const float* __restrict__ a2, unsigned short* __restrict__ abf,
                                            const int* __restrict__ mask,
                                            unsigned long long* __restrict__ mp) {
    const int bid = blockIdx.x;
    if (bid < 4096) {
        __shared__ float t[32][33];
        const int z = bid >> 10, rem = bid & 1023;
        const float* w = z == 0 ? w0 : z == 1 ? w1 : z == 2 ? w2 : w3;
        unsigned short* o = wt + (size_t)z * E * E;
        const int bx = (rem & 31) * 32, by = (rem >> 5) * 32;
        const int tx = threadIdx.x & 31, ty = threadIdx.x >> 5;
        for (int i = 0; i < 32; i += 8)
            t[ty + i][tx] = w[(size_t)(by + ty + i) * E + bx + tx];
        __syncthreads();
        for (int i = 0; i < 32; i += 8)
            o[(size_t)(bx + ty + i) * E + by + tx] = f2bf(t[tx][ty + i]);
    } else if (bid < 10240) {
        const int idx = bid - 4096;
        const int y = idx >> 11, x = idx & 2047;
        const float* s = y == 0 ? a0 : y == 1 ? a1 : a2;
        unsigned short* d = abf + (size_t)y * BATCH * SEQ * E;
        const size_t i = ((size_t)x * 256 + threadIdx.x) * 8;
        const float4 v0 = *(const float4*)&s[i];
        const float4 v1 = *(const float4*)&s[i + 4];
        s16x8 v;
        v[0] = (short)f2bf(v0.x); v[1] = (short)f2bf(v0.y); v[2] = (short)f2bf(v0.z); v[3] = (short)f2bf(v0.w);
        v[4] = (short)f2bf(v1.x); v[5] = (short)f2bf(v1.y); v[6] = (short)f2bf(v1.z); v[7] = (short)f2bf(v1.w);
        *(s16x8*)&d[i] = v;
    } else {
        const int bm = bid - 10240;
        const int w = threadIdx.x >> 6, l = threadIdx.x & 63;
        const size_t wbase = ((size_t)bm * 4 + w) * 16;
        for (int i = 0; i < 16; i++) {
            const size_t widx = wbase + i;  // = (b*SEQ + q)*NKW + t
            const int mv = mask[widx * 64 + l];
            const unsigned long long bits = __ballot(mv != 0);
            if (l == 0) mp[widx] = bits;
        }
    }
}

// ---------------- V transpose: vb[b*S+s][e] -> vbT[b*E+e][s] ----------------
__global__ __launch_bounds__(256) void vtrans(const unsigned short* __restrict__ v,
                                              unsigned short* __restrict__ vt) {
    __shared__ unsigned short t[32][33];
    const int b = blockIdx.z;
    const int s0 = blockIdx.x * 32, e0 = blockIdx.y * 32;
    const int tx = threadIdx.x & 31, ty = threadIdx.x >> 5;
    for (int i = 0; i < 32; i += 8)
        t[ty + i][tx] = v[((size_t)b * SEQ + s0 + ty + i) * E + e0 + tx];
    __syncthreads();
    for (int i = 0; i < 32; i += 8)
        vt[((size_t)b * E + e0 + ty + i) * SEQ + s0 + tx] = t[tx][ty + i];
}

// ---------------- m97-style GEMM: C = (A @ Bt^T + bias) * scale -------------
// XCD-aware block swizzle: nwg = 8*32 = 256 per z (divisible by 8 ->
// bijective). Chunked mapping gives each XCD 4 contiguous m-panels x all n:
// working set 1MB A + 2MB B = 3MB < 4MB per-XCD L2.
template <int OUT_F32, int N_BATCH>
__global__ __launch_bounds__(256) void gemm128(const unsigned short* __restrict__ A,
                                               const unsigned short* __restrict__ Bt,
                                               const float* __restrict__ b0,
                                               const float* __restrict__ b1,
                                               const float* __restrict__ b2,
                                               void* __restrict__ Cv,
                                               float scale0) {
    __shared__ __attribute__((aligned(16))) unsigned short As[128 * 32];
    __shared__ __attribute__((aligned(16))) unsigned short Bs[128 * 32];
    const int z = N_BATCH > 1 ? blockIdx.z : 0;
    const float* bias = z == 0 ? b0 : z == 1 ? b1 : b2;
    const float scale = (N_BATCH > 1 && z > 0) ? 1.0f : scale0;
    A += (size_t)z * BATCH * SEQ * E;
    Bt += (size_t)z * E * E;

    const int tid = threadIdx.x;
    const int w = tid >> 6, l = tid & 63;
    const int lg = l >> 4, lr = l & 15;
    // XCD swizzle (bijective: 256 % 8 == 0)
    const int id = blockIdx.y * 8 + blockIdx.x;
    const int swz = (id & 7) * 32 + (id >> 3);
    const int m0 = (swz >> 3) * 128, n0 = (swz & 7) * 128;
    const int wr = (w >> 1) * 64, wc = (w & 1) * 64;

    const int srow = w * 16 + (l >> 2);
    const int scol = (l & 3) * 8;
    const unsigned short* gA = A + (size_t)(m0 + srow) * E + scol;
    const unsigned short* gB = Bt + (size_t)(n0 + srow) * E + scol;
    unsigned short* lA = As + w * 16 * 32;
    unsigned short* lB = Bs + w * 16 * 32;

    f32x4 acc[4][4] = {};

    for (int k0 = 0; k0 < E; k0 += 32) {
        __syncthreads();
        gld_lds16(gA + k0, lA);
        gld_lds16(gA + (size_t)64 * E + k0, lA + 64 * 32);
        gld_lds16(gB + k0, lB);
        gld_lds16(gB + (size_t)64 * E + k0, lB + 64 * 32);
        __syncthreads();
        s16x8 af[4], bf[4];
#pragma unroll
        for (int i = 0; i < 4; i++)
            af[i] = *(const s16x8*)&As[(wr + i * 16 + lr) * 32 + lg * 8];
#pragma unroll
        for (int j = 0; j < 4; j++)
            bf[j] = *(const s16x8*)&Bs[(wc + j * 16 + lr) * 32 + lg * 8];
        __builtin_amdgcn_s_setprio(1);
#pragma unroll
        for (int i = 0; i < 4; i++)
#pragma unroll
            for (int j = 0; j < 4; j++)
                acc[i][j] = __builtin_amdgcn_mfma_f32_16x16x32_bf16(af[i], bf[j], acc[i][j], 0, 0, 0);
        __builtin_amdgcn_s_setprio(0);
    }

    unsigned short* Co = (unsigned short*)Cv + (size_t)z * BATCH * SEQ * E;
#pragma unroll
    for (int i = 0; i < 4; i++) {
#pragma unroll
        for (int j = 0; j < 4; j++) {
            const int n = n0 + wc + j * 16 + lr;
            const float bv = bias[n];
#pragma unroll
            for (int r = 0; r < 4; r++) {
                const int m = m0 + wr + i * 16 + lg * 4 + r;
                const float v = (acc[i][j][r] + bv) * scale;
                if (OUT_F32) ((float*)Cv)[(size_t)m * E + n] = v;
                else Co[(size_t)m * E + n] = f2bf(v);
            }
        }
    }
}

// ---------------- flash attention (R8-proven core, byte-exact, FROZEN) ------
// log2-domain online softmax, defer-max THR=8, row-sum via MFMA(P, ones).
// LDS 32 KB: K/V double-buffered [64][64] with swizzle ((row>>1)&7)<<4;
// P-relayout buffer ALIASED into Kl[1-buf] (dead half) — wave w's P region
// == exactly the rows wave w re-stages, so the overlap is wave-private.
// Mask u64 loads hoisted to loop TOP (latency hidden under QK^T MFMAs).
// FROZEN: R10/R13 proved this design is schedule-sensitive (launch_bounds
// alone broke it) — no scheduling/sync perturbations without a race-screen.
__global__ __launch_bounds__(256) void attn(const unsigned short* __restrict__ qb,
                                            const unsigned short* __restrict__ kb,
                                            const unsigned short* __restrict__ vbT,
                                            const unsigned long long* __restrict__ maskp,
                                            unsigned short* __restrict__ ctx) {
    __shared__ __attribute__((aligned(16))) unsigned short Kl[2][64 * 64];
    __shared__ __attribute__((aligned(16))) unsigned short Vl[2][64 * 64];

    const int tid = threadIdx.x;
    const int w = tid >> 6, l = tid & 63, lg = l >> 4, lr = l & 15;
    // XCD swizzle: each XCD gets 128 consecutive (b,h,qt) units = 4 whole heads
    const int u = (blockIdx.x & 7) * 128 + (blockIdx.x >> 3);
    const int qt = u & 31, h = (u >> 5) & 15, b = u >> 9;
    const int q0 = qt * 64 + w * 16;

    const unsigned short* qh = qb + (size_t)b * SEQ * E + h * DK;
    const unsigned short* kh = kb + (size_t)b * SEQ * E + h * DK;
    const unsigned short* vt = vbT + ((size_t)b * E + h * DK) * SEQ;
    const unsigned long long* mp = maskp + (size_t)b * SEQ * NKW;

    const s16x8 aq0 = *(const s16x8*)&qh[(size_t)(q0 + lr) * E + lg * 8];
    const s16x8 aq1 = *(const s16x8*)&qh[(size_t)(q0 + lr) * E + 32 + lg * 8];

    s16x8 bone;
#pragma unroll
    for (int i = 0; i < 8; i++) bone[i] = (short)0x3F80;  // bf16 1.0

    const int sr = tid >> 2, sc = (tid & 3) * 8;
    const unsigned short* gK = kh + (size_t)sr * E + sc;
    const unsigned short* gV = vt + (size_t)sr * SEQ + sc;
    const int ssw = ((sr >> 1) & 7) << 4;
    const int wsw0 = (sr * 128 + sc * 2) ^ ssw;
    const int wsw1 = (sr * 128 + sc * 2 + 64) ^ ssw;

    f32x4 o[4] = {};
    f32x4 osum = {};
    float mrun[4] = {-1e30f, -1e30f, -1e30f, -1e30f};

    s16x8 kr0, kr1, vr0, vr1;
    kr0 = *(const s16x8*)(gK);
    kr1 = *(const s16x8*)(gK + 32);
    vr0 = *(const s16x8*)(gV);
    vr1 = *(const s16x8*)(gV + 32);
    *(s16x8*)((char*)&Kl[0][0] + wsw0) = kr0;
    *(s16x8*)((char*)&Kl[0][0] + wsw1) = kr1;
    *(s16x8*)((char*)&Vl[0][0] + wsw0) = vr0;
    *(s16x8*)((char*)&Vl[0][0] + wsw1) = vr1;
    __syncthreads();

    for (int t = 0; t < NKW; ++t) {
        const int buf = t & 1;

        // ---- mask words for THIS tile, issued early (hidden under QK^T) ----
        unsigned long long mwv[4];
#pragma unroll
        for (int r = 0; r < 4; r++)
            mwv[r] = mp[(size_t)(q0 + lg * 4 + r) * NKW + t];

        // ---- K/V prefetch for t+1 ----
        if (t + 1 < NKW) {
            const size_t kof = (size_t)(t + 1) * 64;
            kr0 = *(const s16x8*)(gK + kof * E);
            kr1 = *(const s16x8*)(gK + kof * E + 32);
            vr0 = *(const s16x8*)(gV + kof);
            vr1 = *(const s16x8*)(gV + kof + 32);
        }

        // ---- QK^T (log2-domain scores; col lr of mfma kt = K row 2lr+..) ----
        f32x4 s[4] = {};
        const char* kbse = (const char*)&Kl[buf][0];
        __builtin_amdgcn_s_setprio(1);
#pragma unroll
        for (int kt = 0; kt < 4; kt++) {
            const int row = 2 * lr + (kt & 1) + 32 * (kt >> 1);
            const int sw = (lr & 7) << 4;  // == ((row>>1)&7)<<4
            const s16x8 b0 = *(const s16x8*)(kbse + row * 128 + ((lg << 4) ^ sw));
            const s16x8 b1 = *(const s16x8*)(kbse + row * 128 + ((64 + (lg << 4)) ^ sw));
            s[kt] = __builtin_amdgcn_mfma_f32_16x16x32_bf16(aq0, b0, s[kt], 0, 0, 0);
            s[kt] = __builtin_amdgcn_mfma_f32_16x16x32_bf16(aq1, b1, s[kt], 0, 0, 0);
        }
        __builtin_amdgcn_s_setprio(0);

        // ---- masked softmax: defer-max (THR=8 in log2 domain) ----
        // lane's scores: s[0]=k(2lr), s[1]=k(2lr+1), s[2]=k(2lr+32), s[3]=k(2lr+33)
        float v[4][4], pmax[4];
#pragma unroll
        for (int r = 0; r < 4; r++) {
            const unsigned long long mw = mwv[r];
            const unsigned int mlo = (unsigned int)mw, mhi = (unsigned int)(mw >> 32);
            v[r][0] = ((mlo >> (2 * lr)) & 1) ? s[0][r] : 1.442695e-8f;
            v[r][1] = ((mlo >> (2 * lr + 1)) & 1) ? s[1][r] : 1.442695e-8f;
            v[r][2] = ((mhi >> (2 * lr)) & 1) ? s[2][r] : 1.442695e-8f;
            v[r][3] = ((mhi >> (2 * lr + 1)) & 1) ? s[3][r] : 1.442695e-8f;
            pmax[r] = fmaxf(fmaxf(v[r][0], v[r][1]), fmaxf(v[r][2], v[r][3]));
        }
        const float dmax = fmaxf(fmaxf(pmax[0] - mrun[0], pmax[1] - mrun[1]),
                                 fmaxf(pmax[2] - mrun[2], pmax[3] - mrun[3]));
        if (!__all(dmax <= 8.0f)) {
#pragma unroll
            for (int r = 0; r < 4; r++) {
                float mx = pmax[r];
                mx = fmaxf(mx, __shfl_xor(mx, 1));
                mx = fmaxf(mx, __shfl_xor(mx, 2));
                mx = fmaxf(mx, __shfl_xor(mx, 4));
                mx = fmaxf(mx, __shfl_xor(mx, 8));
                const float mn = fmaxf(mrun[r], mx);
                const float alpha = __builtin_amdgcn_exp2f(mrun[r] - mn);
                mrun[r] = mn;
                osum[r] *= alpha;
#pragma unroll
                for (int dt = 0; dt < 4; dt++) o[dt][r] *= alpha;
            }
        }

        // ---- P = exp2(v - m) -> cvt_pk -> b32 writes into Kl[1-buf] (P region) ----
        char* plw = (char*)&Kl[buf ^ 1][0] + w * 2048;
#pragma unroll
        for (int r = 0; r < 4; r++) {
            const int q = lg * 4 + r;
            const float p0 = __builtin_amdgcn_exp2f(v[r][0] - mrun[r]);
            const float p1 = __builtin_amdgcn_exp2f(v[r][1] - mrun[r]);
            const float p2 = __builtin_amdgcn_exp2f(v[r][2] - mrun[r]);
            const float p3 = __builtin_amdgcn_exp2f(v[r][3] - mrun[r]);
            unsigned int pk01, pk23;
            asm("v_cvt_pk_bf16_f32 %0, %1, %2" : "=v"(pk01) : "v"(p0), "v"(p1));
            asm("v_cvt_pk_bf16_f32 %0, %1, %2" : "=v"(pk23) : "v"(p2), "v"(p3));
            const int psw = (q & 7) << 4;
            *(unsigned int*)(plw + q * 128 + ((lr * 4) ^ psw)) = pk01;       // k=2lr,2lr+1
            *(unsigned int*)(plw + q * 128 + ((64 + lr * 4) ^ psw)) = pk23;  // k=2lr+32,+33
        }
        const int swp = (lr & 7) << 4;
        const s16x8 ap0 = *(const s16x8*)(plw + lr * 128 + ((lg << 4) ^ swp));
        const s16x8 ap1 = *(const s16x8*)(plw + lr * 128 + ((64 + (lg << 4)) ^ swp));

        // ---- PV + row-sum via MFMA ----
        const char* vbse = (const char*)&Vl[buf][0];
        __builtin_amdgcn_s_setprio(1);
        osum = __builtin_amdgcn_mfma_f32_16x16x32_bf16(ap0, bone, osum, 0, 0, 0);
        osum = __builtin_amdgcn_mfma_f32_16x16x32_bf16(ap1, bone, osum, 0, 0, 0);
#pragma unroll
        for (int dt = 0; dt < 4; dt++) {
            const int row = dt * 16 + lr;
            const int sw = ((row >> 1) & 7) << 4;
            const s16x8 bv0 = *(const s16x8*)(vbse + row * 128 + ((lg << 4) ^ sw));
            const s16x8 bv1 = *(const s16x8*)(vbse + row * 128 + ((64 + (lg << 4)) ^ sw));
            o[dt] = __builtin_amdgcn_mfma_f32_16x16x32_bf16(ap0, bv0, o[dt], 0, 0, 0);
            o[dt] = __builtin_amdgcn_mfma_f32_16x16x32_bf16(ap1, bv1, o[dt], 0, 0, 0);
        }
        __builtin_amdgcn_s_setprio(0);

        // ---- stage next tile (wave w overwrites exactly its own P region) ----
        if (t + 1 < NKW) {
            const int nb = buf ^ 1;
            *(s16x8*)((char*)&Kl[nb][0] + wsw0) = kr0;
            *(s16x8*)((char*)&Kl[nb][0] + wsw1) = kr1;
            *(s16x8*)((char*)&Vl[nb][0] + wsw0) = vr0;
            *(s16x8*)((char*)&Vl[nb][0] + wsw1) = vr1;
        }
        __syncthreads();
    }

#pragma unroll
    for (int dt = 0; dt < 4; dt++) {
#pragma unroll
        for (int r = 0; r < 4; r++) {
            const int q = q0 + lg * 4 + r;
            const float val = o[dt][r] / osum[r];
            ctx[(size_t)(b * SEQ + q) * E + h * DK + dt * 16 + lr] = f2bf(val);
        }
    }
}

extern "C" void kernel_launch(void* const* d_in, const int* in_sizes, int n_in,
                              void* d_out, int out_size, void* d_ws, size_t ws_size,
                              hipStream_t stream) {
    const float* query = (const float*)d_in[0];
    const float* key   = (const float*)d_in[1];
    const float* value = (const float*)d_in[2];
    const int*   mask  = (const int*)d_in[3];
    const float* wq = (const float*)d_in[4];
    const float* bq = (const float*)d_in[5];
    const float* wk = (const float*)d_in[6];
    const float* bk = (const float*)d_in[7];
    const float* wv = (const float*)d_in[8];
    const float* bv = (const float*)d_in[9];
    const float* wo = (const float*)d_in[10];
    const float* bo = (const float*)d_in[11];

    unsigned short* wt   = (unsigned short*)d_ws;            // 4 x E x E (q,k,v,o)
    unsigned short* wt_o = wt + (size_t)3 * E * E;
    unsigned short* qbf  = wt + (size_t)4 * E * E;           // 3 x B*S*E contiguous
    unsigned short* qb   = qbf + (size_t)3 * BATCH * SEQ * E;  // 3 x B*S*E contiguous
    unsigned short* kb   = qb + (size_t)BATCH * SEQ * E;
    unsigned short* vb   = kb + (size_t)BATCH * SEQ * E;
    unsigned short* vbT  = vb + (size_t)BATCH * SEQ * E;
    unsigned short* ctx  = vbT + (size_t)BATCH * SEQ * E;
    unsigned long long* maskp = (unsigned long long*)(ctx + (size_t)BATCH * SEQ * E);

    prep<<<dim3(12288), 256, 0, stream>>>(wq, wk, wv, wo, wt, query, key, value, qbf, mask, maskp);

    // QKV projections batched; Q pre-scaled by 0.125*log2(e)
    gemm128<0, 3><<<dim3(E / 128, (BATCH * SEQ) / 128, 3), 256, 0, stream>>>(
        qbf, wt, bq, bk, bv, qb, 0.125f * LOG2E);

    vtrans<<<dim3(SEQ / 32, E / 32, BATCH), 256, 0, stream>>>(vb, vbT);

    attn<<<dim3(SEQ / 64 * NH * BATCH), 256, 0, stream>>>(qb, kb, vbT, maskp, ctx);

    gemm128<1, 1><<<dim3(E / 128, (BATCH * SEQ) / 128), 256, 0, stream>>>(
        ctx, wt_o, bo, bo, bo, (float*)d_out, 1.0f);
}